// Round 17
// baseline (349.265 us; speedup 1.0000x reference)
//
#include <hip/hip_runtime.h>

#define B_ 4
#define S_ 2048
#define D_ 512
#define H_ 8
#define DP_ 64
#define NT_ (S_/64)

typedef __attribute__((ext_vector_type(4))) float f32x4;
typedef __attribute__((ext_vector_type(8))) short short8;
typedef __attribute__((ext_vector_type(4))) int i32x4;

__device__ __forceinline__ short f2bf(float f){
  unsigned u = __float_as_uint(f);
  u += 0x7fff + ((u >> 16) & 1);   // round-to-nearest-even
  return (short)(u >> 16);
}

__device__ __forceinline__ int cvtpk(float lo, float hi){
  int r;
  asm("v_cvt_pk_bf16_f32 %0, %1, %2" : "=v"(r) : "v"(lo), "v"(hi));
  return r;
}

// GEMM swizzle: XOR 8-elem granule with row&7
#define SWZ(r, kb) ((r)*64 + ((kb) ^ (((r)&7)<<3)))

template<int NC>
__device__ __forceinline__ void stage_swz(const short* __restrict__ g, int rowStride,
                                          short* shbase, int w, int l){
  #pragma unroll
  for(int i = 0; i < NC; ++i){
    int byte = (w*NC + i)*1024 + l*16;
    int row = byte >> 7;
    int gs = ((byte >> 4) & 7) ^ (row & 7);
    const short* src = g + (size_t)row*rowStride + gs*8;
    __builtin_amdgcn_global_load_lds((const __attribute__((address_space(1))) void*)src,
        (__attribute__((address_space(3))) void*)(shbase + (w*NC + i)*512), 16, 0, 0);
  }
}

// ---------------- pre-pass: weight transposes + mask bias (exp2 domain) ----------------
__global__ __launch_bounds__(256) void k_pre(const int* __restrict__ mask,
        const float* __restrict__ w0, const float* __restrict__ w1,
        const float* __restrict__ w2, const float* __restrict__ w3,
        short* __restrict__ wT, float* __restrict__ mb){
  __shared__ float tt[32][33];
  const int bi = blockIdx.x, t = threadIdx.x;
  if(bi < 1024){
    const int z = bi >> 8;
    const float* w = z == 0 ? w0 : z == 1 ? w1 : z == 2 ? w2 : w3;
    short* wt = wT + z * 262144;
    const int bxy = bi & 255;
    const int bx = (bxy & 15) * 32, by = (bxy >> 4) * 32;
    const int tx = t & 31, ty = t >> 5;
    #pragma unroll
    for(int i = 0; i < 32; i += 8) tt[ty + i][tx] = w[(by + ty + i) * D_ + bx + tx];
    __syncthreads();
    #pragma unroll
    for(int i = 0; i < 32; i += 8) wt[(bx + ty + i) * D_ + by + tx] = f2bf(tt[tx][ty + i]);
  } else {
    int i = (bi - 1024) * 256 + t;
    mb[i] = mask[i] ? -1.442695041e9f : 0.0f;
  }
}

// ---------------- fused QKV GEMM: X f32 read + convert in-staging ----------------
__global__ __launch_bounds__(256) void k_gemm_qkv(const float* __restrict__ qf,
        const float* __restrict__ kf, const float* __restrict__ vf,
        const short* __restrict__ WTall, const float* __restrict__ b0,
        const float* __restrict__ b1, const float* __restrict__ b2,
        short* __restrict__ qh, short* __restrict__ kh, short* __restrict__ vvt){
  __shared__ __align__(16) short As[8192];
  __shared__ __align__(16) short Bs[8192];
  const int z = blockIdx.z;
  const float* X = z == 0 ? qf : (z == 1 ? kf : vf);
  const short* WT = WTall + (size_t)z * (D_*D_);
  const float* bias = z==0 ? b0 : (z==1 ? b1 : b2);
  const int t = threadIdx.x, l = t & 63, w = t >> 6;
  const int lr = l & 15, lg = l >> 4;
  const int m0 = blockIdx.x * 128, n0 = blockIdx.y * 128;
  const int wr = w >> 1, wc = w & 1;
  const float* Xb = X + (size_t)m0 * D_;
  const short* Wb = WT + (size_t)n0 * D_;
  f32x4 acc[4][4] = {};
  for(int kt = 0; kt < D_ / 64; ++kt){
    #pragma unroll
    for(int i = 0; i < 4; ++i){
      int e = t + 256 * i;
      int row = e >> 3, c8 = (e & 7) * 8;
      const float* src = Xb + (size_t)row * D_ + kt * 64 + c8;
      float4 f0 = *reinterpret_cast<const float4*>(src);
      float4 f1 = *reinterpret_cast<const float4*>(src + 4);
      i32x4 pk;
      pk[0] = cvtpk(f0.x, f0.y); pk[1] = cvtpk(f0.z, f0.w);
      pk[2] = cvtpk(f1.x, f1.y); pk[3] = cvtpk(f1.z, f1.w);
      *reinterpret_cast<i32x4*>(&As[SWZ(row, c8)]) = pk;
    }
    stage_swz<4>(Wb + kt*64, D_, Bs, w, l);
    __syncthreads();
    #pragma unroll
    for(int ks = 0; ks < 2; ++ks){
      const int kb = ks*32 + lg*8;
      short8 a[4], b[4];
      #pragma unroll
      for(int mt = 0; mt < 4; ++mt)
        a[mt] = *reinterpret_cast<const short8*>(&As[SWZ(wr*64 + mt*16 + lr, kb)]);
      #pragma unroll
      for(int nt = 0; nt < 4; ++nt)
        b[nt] = *reinterpret_cast<const short8*>(&Bs[SWZ(wc*64 + nt*16 + lr, kb)]);
      __builtin_amdgcn_s_setprio(1);
      #pragma unroll
      for(int mt = 0; mt < 4; ++mt)
        #pragma unroll
        for(int nt = 0; nt < 4; ++nt)
          acc[mt][nt] = __builtin_amdgcn_mfma_f32_16x16x32_bf16(a[mt], b[nt], acc[mt][nt], 0, 0, 0);
      __builtin_amdgcn_s_setprio(0);
    }
    __syncthreads();
  }
  #pragma unroll
  for(int mt = 0; mt < 4; ++mt){
    #pragma unroll
    for(int nt = 0; nt < 4; ++nt){
      const int n = n0 + wc*64 + nt*16 + lr;
      const int m4 = m0 + wr*64 + mt*16 + lg*4;
      float vals[4];
      #pragma unroll
      for(int r = 0; r < 4; ++r) vals[r] = acc[mt][nt][r] + bias[n];
      if(z == 2){
        short4 pv4;
        pv4.x = f2bf(vals[0]); pv4.y = f2bf(vals[1]); pv4.z = f2bf(vals[2]); pv4.w = f2bf(vals[3]);
        *reinterpret_cast<short4*>(&vvt[
            (((size_t)((m4 >> 11) * H_ + (n >> 6))) * DP_ + (n & 63)) * S_ + (m4 & 2047)]) = pv4;
      } else {
        short* dst = z == 0 ? qh : kh;
        #pragma unroll
        for(int r = 0; r < 4; ++r){
          int m = m4 + r;
          dst[(((size_t)((m >> 11) * H_ + (n >> 6))) * S_ + (m & 2047)) * DP_ + (n & 63)] = f2bf(vals[r]);
        }
      }
    }
  }
}

// ---------------- out GEMM: ctx[8192,512]bf16 @ woT + bo -> f32 ----------------
__global__ __launch_bounds__(256) void k_gemm_out(const short* __restrict__ X,
        const short* __restrict__ WT, const float* __restrict__ bias,
        float* __restrict__ Out){
  __shared__ __align__(16) short As[8192];
  __shared__ __align__(16) short Bs[8192];
  const int t = threadIdx.x, l = t & 63, w = t >> 6;
  const int lr = l & 15, lg = l >> 4;
  const int m0 = blockIdx.x * 128, n0 = blockIdx.y * 128;
  const int wr = w >> 1, wc = w & 1;
  const short* Xb = X + (size_t)m0 * D_;
  const short* Wb = WT + (size_t)n0 * D_;
  f32x4 acc[4][4] = {};
  for(int kt = 0; kt < D_ / 64; ++kt){
    stage_swz<4>(Xb + kt*64, D_, As, w, l);
    stage_swz<4>(Wb + kt*64, D_, Bs, w, l);
    __syncthreads();
    #pragma unroll
    for(int ks = 0; ks < 2; ++ks){
      const int kb = ks*32 + lg*8;
      short8 a[4], b[4];
      #pragma unroll
      for(int mt = 0; mt < 4; ++mt)
        a[mt] = *reinterpret_cast<const short8*>(&As[SWZ(wr*64 + mt*16 + lr, kb)]);
      #pragma unroll
      for(int nt = 0; nt < 4; ++nt)
        b[nt] = *reinterpret_cast<const short8*>(&Bs[SWZ(wc*64 + nt*16 + lr, kb)]);
      __builtin_amdgcn_s_setprio(1);
      #pragma unroll
      for(int mt = 0; mt < 4; ++mt)
        #pragma unroll
        for(int nt = 0; nt < 4; ++nt)
          acc[mt][nt] = __builtin_amdgcn_mfma_f32_16x16x32_bf16(a[mt], b[nt], acc[mt][nt], 0, 0, 0);
      __builtin_amdgcn_s_setprio(0);
    }
    __syncthreads();
  }
  #pragma unroll
  for(int mt = 0; mt < 4; ++mt){
    #pragma unroll
    for(int nt = 0; nt < 4; ++nt){
      const int n = n0 + wc*64 + nt*16 + lr;
      const int m4 = m0 + wr*64 + mt*16 + lg*4;
      #pragma unroll
      for(int r = 0; r < 4; ++r)
        Out[(size_t)(m4 + r) * D_ + n] = acc[mt][nt][r] + bias[n];
    }
  }
}

// ---------------- fused attention: barrier-free direct-operand waves ----------------
// 8 waves, q-tile 128. Wave (wq=w&3, g=w>>2): tiles kt=2i+g, q-rows wq*32..+31 (2 qs).
// ALL operands (Q,K,V,mask) read directly from global (L2-resident: ~2MB/XCD).
// No LDS staging, no barriers in main loops. LDS only: psums 1KB + Oc 33KB.
// Two __syncthreads(): psum exchange, o-combine.
__global__ __launch_bounds__(512, 4) void k_attn(const short* __restrict__ qh,
                                                 const short* __restrict__ kh,
                                                 const short* __restrict__ vt,
                                                 const float* __restrict__ mb,
                                                 float* __restrict__ attn,
                                                 short* __restrict__ ctx){
  __shared__ float ShF[8576];                      // Ps_[0,256) | Oc[256,8576)
  float* Ps_ = ShF;
  float* Oc  = ShF + 256;
  const int t = threadIdx.x, l = t & 63, w = t >> 6;
  const int lr = l & 15, lg = l >> 4;
  const int wq = w & 3, g = w >> 2;
  int lin = blockIdx.y * 16 + blockIdx.x;
  int sw = (lin & 7) * 64 + (lin >> 3);
  const int bh = sw >> 4, b = bh >> 3, h = bh & 7;
  const int q0 = (sw & 15) * 128;
  const short* Qb = qh + (size_t)bh * S_ * DP_ + (size_t)q0 * DP_;
  const short* Kb = kh + (size_t)bh * S_ * DP_;
  const short* Vtb = vt + (size_t)bh * DP_ * S_;
  const float* Mbb = mb + b * S_;
  const float scale2 = 0.125f * 1.442695041f;      // exp2 domain

  // Q fragments direct from global (4 x 16B per wave-lane)
  short8 bq[2][2];
  #pragma unroll
  for(int qs = 0; qs < 2; ++qs){
    const short* qr = Qb + (size_t)(wq * 32 + qs * 16 + lr) * DP_;
    bq[qs][0] = *reinterpret_cast<const short8*>(qr + lg * 8);
    bq[qs][1] = *reinterpret_cast<const short8*>(qr + 32 + lg * 8);
  }
  const int grow = ((lr >> 2) << 3) + (lr & 3);    // permuted A-row base

  // ---------------- pass A: partial row sums (no barriers) ----------------
  float ps2[2] = {0.f, 0.f};
  for(int i = 0; i < NT_/2; ++i){
    const int kt = 2*i + g;
    const short* Kt = Kb + (size_t)kt * 64 * DP_;
    const float* Mt = Mbb + kt * 64;
    #pragma unroll
    for(int st = 0; st < 4; ++st){
      const int ks = st >> 1, h4 = st & 1;
      const int row = grow + h4 * 4 + ks * 32;
      const int mcol = ks * 32 + h4 * 4 + lg * 8;
      const float4 mv = *reinterpret_cast<const float4*>(Mt + mcol);
      const short* kr = Kt + (size_t)row * DP_;
      short8 ak0 = *reinterpret_cast<const short8*>(kr + lg * 8);
      short8 ak1 = *reinterpret_cast<const short8*>(kr + 32 + lg * 8);
      __builtin_amdgcn_s_setprio(1);
      f32x4 c0 = {}, c1 = {};
      c0 = __builtin_amdgcn_mfma_f32_16x16x32_bf16(ak0, bq[0][0], c0, 0, 0, 0);
      c0 = __builtin_amdgcn_mfma_f32_16x16x32_bf16(ak1, bq[0][1], c0, 0, 0, 0);
      c1 = __builtin_amdgcn_mfma_f32_16x16x32_bf16(ak0, bq[1][0], c1, 0, 0, 0);
      c1 = __builtin_amdgcn_mfma_f32_16x16x32_bf16(ak1, bq[1][1], c1, 0, 0, 0);
      __builtin_amdgcn_s_setprio(0);
      ps2[0] += __builtin_amdgcn_exp2f(__builtin_fmaf(c0[0], scale2, mv.x));
      ps2[0] += __builtin_amdgcn_exp2f(__builtin_fmaf(c0[1], scale2, mv.y));
      ps2[0] += __builtin_amdgcn_exp2f(__builtin_fmaf(c0[2], scale2, mv.z));
      ps2[0] += __builtin_amdgcn_exp2f(__builtin_fmaf(c0[3], scale2, mv.w));
      ps2[1] += __builtin_amdgcn_exp2f(__builtin_fmaf(c1[0], scale2, mv.x));
      ps2[1] += __builtin_amdgcn_exp2f(__builtin_fmaf(c1[1], scale2, mv.y));
      ps2[1] += __builtin_amdgcn_exp2f(__builtin_fmaf(c1[2], scale2, mv.z));
      ps2[1] += __builtin_amdgcn_exp2f(__builtin_fmaf(c1[3], scale2, mv.w));
    }
  }
  #pragma unroll
  for(int qs = 0; qs < 2; ++qs){
    ps2[qs] += __shfl_xor(ps2[qs], 16, 64);
    ps2[qs] += __shfl_xor(ps2[qs], 32, 64);
  }
  Ps_[(w*2 + 0)*16 + lr] = ps2[0];
  Ps_[(w*2 + 1)*16 + lr] = ps2[1];
  __syncthreads();
  const float rinv0 = 1.f / (ps2[0] + Ps_[((w^4)*2 + 0)*16 + lr]);
  const float rinv1 = 1.f / (ps2[1] + Ps_[((w^4)*2 + 1)*16 + lr]);

  // ---------------- pass B: attn write + in-register PV (no barriers) ----------------
  f32x4 o[2][4] = {};
  for(int i = 0; i < NT_/2; ++i){
    const int kt = 2*i + g;
    const short* Kt = Kb + (size_t)kt * 64 * DP_;
    const float* Mt = Mbb + kt * 64;
    i32x4 pav[2][2];
    #pragma unroll
    for(int st = 0; st < 4; ++st){
      const int ks = st >> 1, h4 = st & 1;
      const int row = grow + h4 * 4 + ks * 32;
      const int mcol = ks * 32 + h4 * 4 + lg * 8;
      const float4 mv = *reinterpret_cast<const float4*>(Mt + mcol);
      const short* kr = Kt + (size_t)row * DP_;
      short8 ak0 = *reinterpret_cast<const short8*>(kr + lg * 8);
      short8 ak1 = *reinterpret_cast<const short8*>(kr + 32 + lg * 8);
      __builtin_amdgcn_s_setprio(1);
      f32x4 c0 = {}, c1 = {};
      c0 = __builtin_amdgcn_mfma_f32_16x16x32_bf16(ak0, bq[0][0], c0, 0, 0, 0);
      c0 = __builtin_amdgcn_mfma_f32_16x16x32_bf16(ak1, bq[0][1], c0, 0, 0, 0);
      c1 = __builtin_amdgcn_mfma_f32_16x16x32_bf16(ak0, bq[1][0], c1, 0, 0, 0);
      c1 = __builtin_amdgcn_mfma_f32_16x16x32_bf16(ak1, bq[1][1], c1, 0, 0, 0);
      __builtin_amdgcn_s_setprio(0);
      float4 pw0, pw1;
      pw0.x = __builtin_amdgcn_exp2f(__builtin_fmaf(c0[0], scale2, mv.x)) * rinv0;
      pw0.y = __builtin_amdgcn_exp2f(__builtin_fmaf(c0[1], scale2, mv.y)) * rinv0;
      pw0.z = __builtin_amdgcn_exp2f(__builtin_fmaf(c0[2], scale2, mv.z)) * rinv0;
      pw0.w = __builtin_amdgcn_exp2f(__builtin_fmaf(c0[3], scale2, mv.w)) * rinv0;
      pw1.x = __builtin_amdgcn_exp2f(__builtin_fmaf(c1[0], scale2, mv.x)) * rinv1;
      pw1.y = __builtin_amdgcn_exp2f(__builtin_fmaf(c1[1], scale2, mv.y)) * rinv1;
      pw1.z = __builtin_amdgcn_exp2f(__builtin_fmaf(c1[2], scale2, mv.z)) * rinv1;
      pw1.w = __builtin_amdgcn_exp2f(__builtin_fmaf(c1[3], scale2, mv.w)) * rinv1;
      const int qr = q0 + wq * 32 + lr;
      *reinterpret_cast<float4*>(&attn[((size_t)bh * S_ + qr) * S_ + kt * 64 + mcol]) = pw0;
      *reinterpret_cast<float4*>(&attn[((size_t)bh * S_ + qr + 16) * S_ + kt * 64 + mcol]) = pw1;
      pav[0][ks][h4 * 2 + 0] = cvtpk(pw0.x, pw0.y);
      pav[0][ks][h4 * 2 + 1] = cvtpk(pw0.z, pw0.w);
      pav[1][ks][h4 * 2 + 0] = cvtpk(pw1.x, pw1.y);
      pav[1][ks][h4 * 2 + 1] = cvtpk(pw1.z, pw1.w);
    }
    #pragma unroll
    for(int ks = 0; ks < 2; ++ks){
      short8 pa0 = __builtin_bit_cast(short8, pav[0][ks]);
      short8 pa1 = __builtin_bit_cast(short8, pav[1][ks]);
      #pragma unroll
      for(int dt = 0; dt < 4; ++dt){
        short8 vb = *reinterpret_cast<const short8*>(
            Vtb + (size_t)(dt * 16 + lr) * S_ + kt * 64 + ks * 32 + lg * 8);
        __builtin_amdgcn_s_setprio(1);
        o[0][dt] = __builtin_amdgcn_mfma_f32_16x16x32_bf16(pa0, vb, o[0][dt], 0, 0, 0);
        o[1][dt] = __builtin_amdgcn_mfma_f32_16x16x32_bf16(pa1, vb, o[1][dt], 0, 0, 0);
        __builtin_amdgcn_s_setprio(0);
      }
    }
  }

  // ---------------- o-combine across k-groups, write ctx ----------------
  if(g == 0){
    #pragma unroll
    for(int qs = 0; qs < 2; ++qs)
      #pragma unroll
      for(int dt = 0; dt < 4; ++dt)
        #pragma unroll
        for(int r = 0; r < 4; ++r)
          Oc[(wq*32 + qs*16 + lg*4 + r) * 65 + dt*16 + lr] = o[qs][dt][r];
  }
  __syncthreads();
  if(g == 1){
    #pragma unroll
    for(int qs = 0; qs < 2; ++qs){
      #pragma unroll
      for(int dt = 0; dt < 4; ++dt){
        #pragma unroll
        for(int r = 0; r < 4; ++r){
          float v = o[qs][dt][r] + Oc[(wq*32 + qs*16 + lg*4 + r) * 65 + dt*16 + lr];
          int qg = q0 + wq*32 + qs*16 + lg*4 + r;
          int dd = h * 64 + dt * 16 + lr;
          ctx[((size_t)b * S_ + qg) * D_ + dd] = f2bf(v);
        }
      }
    }
  }
}

extern "C" void kernel_launch(void* const* d_in, const int* in_sizes, int n_in,
                              void* d_out, int out_size, void* d_ws, size_t ws_size,
                              hipStream_t stream){
  const float* q  = (const float*)d_in[0];
  const float* k  = (const float*)d_in[1];
  const float* v  = (const float*)d_in[2];
  const int* mask = (const int*)d_in[3];
  const float* wq = (const float*)d_in[4];
  const float* bq = (const float*)d_in[5];
  const float* wk = (const float*)d_in[6];
  const float* bk = (const float*)d_in[7];
  const float* wv = (const float*)d_in[8];
  const float* bv = (const float*)d_in[9];
  const float* wo = (const float*)d_in[10];
  const float* bo = (const float*)d_in[11];

  float* out  = (float*)d_out;
  float* attn = out + (size_t)B_ * S_ * D_;

  char* ws = (char*)d_ws;
  short* qh  = (short*)(ws);                       // bf16 [B][H][S][64]
  short* kh  = (short*)(ws + 8388608);
  short* vvt = (short*)(ws + 16777216);            // bf16 [B][H][64][S]
  short* ctx = (short*)(ws + 25165824);            // bf16 [B][S][512]
  short* wT  = (short*)(ws + 33554432);            // bf16 [512][512] x4 transposed
  float* mb  = (float*)(ws + 33554432 + 4 * 524288);  // f32 [B][S] mask bias (exp2 domain)

  hipLaunchKernelGGL(k_pre, dim3(1056), dim3(256), 0, stream,
                     mask, wq, wk, wv, wo, wT, mb);

  hipLaunchKernelGGL(k_gemm_qkv, dim3(64, 4, 3), dim3(256), 0, stream,
                     q, k, v, wT, bq, bk, bv, qh, kh, vvt);

  hipLaunchKernelGGL(k_attn, dim3(16, 32), dim3(512), 0, stream, qh, kh, vvt, mb, attn, ctx);

  hipLaunchKernelGGL(k_gemm_out, dim3(64, 4), dim3(256), 0, stream, ctx, wT + 3 * 262144, bo, out);
}

// Round 18
// 263.620 us; speedup vs baseline: 1.3249x; 1.3249x over previous
//
#include <hip/hip_runtime.h>

#define B_ 4
#define S_ 2048
#define D_ 512
#define H_ 8
#define DP_ 64
#define NT2_ (S_/32)

typedef __attribute__((ext_vector_type(4))) float f32x4;
typedef __attribute__((ext_vector_type(8))) short short8;
typedef __attribute__((ext_vector_type(4))) int i32x4;

__device__ __forceinline__ short f2bf(float f){
  unsigned u = __float_as_uint(f);
  u += 0x7fff + ((u >> 16) & 1);   // round-to-nearest-even
  return (short)(u >> 16);
}

__device__ __forceinline__ int cvtpk(float lo, float hi){
  int r;
  asm("v_cvt_pk_bf16_f32 %0, %1, %2" : "=v"(r) : "v"(lo), "v"(hi));
  return r;
}

// GEMM swizzle: XOR 8-elem granule with row&7
#define SWZ(r, kb) ((r)*64 + ((kb) ^ (((r)&7)<<3)))
// attn K swizzle (2-way free for linear + permuted 32-row reads)
#define F2(r) ((((r)&3)) | ((((r)>>3)&1)<<2))
#define SWZ2(r, kb) ((r)*64 + ((kb) ^ (F2(r)<<3)))

#define WAITV(N) do{ asm volatile("s_waitcnt vmcnt(" #N ")" ::: "memory"); }while(0)
#define BAR() do{ __builtin_amdgcn_s_barrier(); __builtin_amdgcn_sched_barrier(0); }while(0)

// 128B-row staging (GEMM, 8KB tiles over NW waves)
template<int NC>
__device__ __forceinline__ void stage_swz(const short* __restrict__ g, int rowStride,
                                          short* shbase, int w, int l){
  #pragma unroll
  for(int i = 0; i < NC; ++i){
    int byte = (w*NC + i)*1024 + l*16;
    int row = byte >> 7;
    int gs = ((byte >> 4) & 7) ^ (row & 7);
    const short* src = g + (size_t)row*rowStride + gs*8;
    __builtin_amdgcn_global_load_lds((const __attribute__((address_space(1))) void*)src,
        (__attribute__((address_space(3))) void*)(shbase + (w*NC + i)*512), 16, 0, 0);
  }
}

// attn: stage 32x64 K tile (4KB) with F2 swizzle; 4 waves x 1KB
__device__ __forceinline__ void stage_k32(const short* __restrict__ g,
                                          short* dst, int w, int l){
  int byte = w*1024 + l*16;
  int row = byte >> 7;                      // 0..31
  int gs = ((byte >> 4) & 7) ^ F2(row);
  const short* src = g + (size_t)row*DP_ + gs*8;
  __builtin_amdgcn_global_load_lds((const __attribute__((address_space(1))) void*)src,
      (__attribute__((address_space(3))) void*)(dst + (byte >> 1)), 16, 0, 0);
}
// attn: stage 64x32 V^T tile (4KB), chunk^(d&3) swizzle; rows 64B in global [d][S]
__device__ __forceinline__ void stage_v32(const short* __restrict__ g,
                                          short* dst, int w, int l){
  int byte = w*1024 + l*16;
  int d = byte >> 6;                        // 0..63
  int ch = (byte >> 4) & 3;
  int sc = ch ^ (d & 3);
  const short* src = g + (size_t)d*S_ + sc*8;
  __builtin_amdgcn_global_load_lds((const __attribute__((address_space(1))) void*)src,
      (__attribute__((address_space(3))) void*)(dst + (byte >> 1)), 16, 0, 0);
}

// ---------------- pre-pass: weight transposes + mask bias (exp2 domain) ----------------
__global__ __launch_bounds__(256) void k_pre(const int* __restrict__ mask,
        const float* __restrict__ w0, const float* __restrict__ w1,
        const float* __restrict__ w2, const float* __restrict__ w3,
        short* __restrict__ wT, float* __restrict__ mb){
  __shared__ float tt[32][33];
  const int bi = blockIdx.x, t = threadIdx.x;
  if(bi < 1024){
    const int z = bi >> 8;
    const float* w = z == 0 ? w0 : z == 1 ? w1 : z == 2 ? w2 : w3;
    short* wt = wT + z * 262144;
    const int bxy = bi & 255;
    const int bx = (bxy & 15) * 32, by = (bxy >> 4) * 32;
    const int tx = t & 31, ty = t >> 5;
    #pragma unroll
    for(int i = 0; i < 32; i += 8) tt[ty + i][tx] = w[(by + ty + i) * D_ + bx + tx];
    __syncthreads();
    #pragma unroll
    for(int i = 0; i < 32; i += 8) wt[(bx + ty + i) * D_ + by + tx] = f2bf(tt[tx][ty + i]);
  } else {
    int i = (bi - 1024) * 256 + t;
    mb[i] = mask[i] ? -1.442695041e9f : 0.0f;
  }
}

// ---------------- fused QKV GEMM: X f32 read + convert in-staging ----------------
__global__ __launch_bounds__(256) void k_gemm_qkv(const float* __restrict__ qf,
        const float* __restrict__ kf, const float* __restrict__ vf,
        const short* __restrict__ WTall, const float* __restrict__ b0,
        const float* __restrict__ b1, const float* __restrict__ b2,
        short* __restrict__ qh, short* __restrict__ kh, short* __restrict__ vvt){
  __shared__ __align__(16) short As[8192];
  __shared__ __align__(16) short Bs[8192];
  const int z = blockIdx.z;
  const float* X = z == 0 ? qf : (z == 1 ? kf : vf);
  const short* WT = WTall + (size_t)z * (D_*D_);
  const float* bias = z==0 ? b0 : (z==1 ? b1 : b2);
  const int t = threadIdx.x, l = t & 63, w = t >> 6;
  const int lr = l & 15, lg = l >> 4;
  const int m0 = blockIdx.x * 128, n0 = blockIdx.y * 128;
  const int wr = w >> 1, wc = w & 1;
  const float* Xb = X + (size_t)m0 * D_;
  const short* Wb = WT + (size_t)n0 * D_;
  f32x4 acc[4][4] = {};
  for(int kt = 0; kt < D_ / 64; ++kt){
    #pragma unroll
    for(int i = 0; i < 4; ++i){
      int e = t + 256 * i;
      int row = e >> 3, c8 = (e & 7) * 8;
      const float* src = Xb + (size_t)row * D_ + kt * 64 + c8;
      float4 f0 = *reinterpret_cast<const float4*>(src);
      float4 f1 = *reinterpret_cast<const float4*>(src + 4);
      i32x4 pk;
      pk[0] = cvtpk(f0.x, f0.y); pk[1] = cvtpk(f0.z, f0.w);
      pk[2] = cvtpk(f1.x, f1.y); pk[3] = cvtpk(f1.z, f1.w);
      *reinterpret_cast<i32x4*>(&As[SWZ(row, c8)]) = pk;
    }
    stage_swz<4>(Wb + kt*64, D_, Bs, w, l);
    __syncthreads();
    #pragma unroll
    for(int ks = 0; ks < 2; ++ks){
      const int kb = ks*32 + lg*8;
      short8 a[4], b[4];
      #pragma unroll
      for(int mt = 0; mt < 4; ++mt)
        a[mt] = *reinterpret_cast<const short8*>(&As[SWZ(wr*64 + mt*16 + lr, kb)]);
      #pragma unroll
      for(int nt = 0; nt < 4; ++nt)
        b[nt] = *reinterpret_cast<const short8*>(&Bs[SWZ(wc*64 + nt*16 + lr, kb)]);
      __builtin_amdgcn_s_setprio(1);
      #pragma unroll
      for(int mt = 0; mt < 4; ++mt)
        #pragma unroll
        for(int nt = 0; nt < 4; ++nt)
          acc[mt][nt] = __builtin_amdgcn_mfma_f32_16x16x32_bf16(a[mt], b[nt], acc[mt][nt], 0, 0, 0);
      __builtin_amdgcn_s_setprio(0);
    }
    __syncthreads();
  }
  #pragma unroll
  for(int mt = 0; mt < 4; ++mt){
    #pragma unroll
    for(int nt = 0; nt < 4; ++nt){
      const int n = n0 + wc*64 + nt*16 + lr;
      const int m4 = m0 + wr*64 + mt*16 + lg*4;
      float vals[4];
      #pragma unroll
      for(int r = 0; r < 4; ++r) vals[r] = acc[mt][nt][r] + bias[n];
      if(z == 2){
        short4 pv4;
        pv4.x = f2bf(vals[0]); pv4.y = f2bf(vals[1]); pv4.z = f2bf(vals[2]); pv4.w = f2bf(vals[3]);
        *reinterpret_cast<short4*>(&vvt[
            (((size_t)((m4 >> 11) * H_ + (n >> 6))) * DP_ + (n & 63)) * S_ + (m4 & 2047)]) = pv4;
      } else {
        short* dst = z == 0 ? qh : kh;
        #pragma unroll
        for(int r = 0; r < 4; ++r){
          int m = m4 + r;
          dst[(((size_t)((m >> 11) * H_ + (n >> 6))) * S_ + (m & 2047)) * DP_ + (n & 63)] = f2bf(vals[r]);
        }
      }
    }
  }
}

// ---------------- out GEMM: ctx[8192,512]bf16 @ woT + bo -> f32 ----------------
__global__ __launch_bounds__(256) void k_gemm_out(const short* __restrict__ X,
        const short* __restrict__ WT, const float* __restrict__ bias,
        float* __restrict__ Out){
  __shared__ __align__(16) short As[8192];
  __shared__ __align__(16) short Bs[8192];
  const int t = threadIdx.x, l = t & 63, w = t >> 6;
  const int lr = l & 15, lg = l >> 4;
  const int m0 = blockIdx.x * 128, n0 = blockIdx.y * 128;
  const int wr = w >> 1, wc = w & 1;
  const short* Xb = X + (size_t)m0 * D_;
  const short* Wb = WT + (size_t)n0 * D_;
  f32x4 acc[4][4] = {};
  for(int kt = 0; kt < D_ / 64; ++kt){
    stage_swz<4>(Xb + kt*64, D_, As, w, l);
    stage_swz<4>(Wb + kt*64, D_, Bs, w, l);
    __syncthreads();
    #pragma unroll
    for(int ks = 0; ks < 2; ++ks){
      const int kb = ks*32 + lg*8;
      short8 a[4], b[4];
      #pragma unroll
      for(int mt = 0; mt < 4; ++mt)
        a[mt] = *reinterpret_cast<const short8*>(&As[SWZ(wr*64 + mt*16 + lr, kb)]);
      #pragma unroll
      for(int nt = 0; nt < 4; ++nt)
        b[nt] = *reinterpret_cast<const short8*>(&Bs[SWZ(wc*64 + nt*16 + lr, kb)]);
      __builtin_amdgcn_s_setprio(1);
      #pragma unroll
      for(int mt = 0; mt < 4; ++mt)
        #pragma unroll
        for(int nt = 0; nt < 4; ++nt)
          acc[mt][nt] = __builtin_amdgcn_mfma_f32_16x16x32_bf16(a[mt], b[nt], acc[mt][nt], 0, 0, 0);
      __builtin_amdgcn_s_setprio(0);
    }
    __syncthreads();
  }
  #pragma unroll
  for(int mt = 0; mt < 4; ++mt){
    #pragma unroll
    for(int nt = 0; nt < 4; ++nt){
      const int n = n0 + wc*64 + nt*16 + lr;
      const int m4 = m0 + wr*64 + mt*16 + lg*4;
      #pragma unroll
      for(int r = 0; r < 4; ++r)
        Out[(size_t)(m4 + r) * D_ + n] = acc[mt][nt][r] + bias[n];
    }
  }
}

// ---------------- fused attention: small decoupled blocks ----------------
// 4 waves (256 thr), q-tile 64 (wave w: 16 q-rows), KVBLK=32, 64 iterations/pass.
// 24KB LDS -> 6 blocks/CU, 24 waves/CU, 6 independent barrier groups.
// Pass A: K ring-3, stage kt+2 after BAR, WAITV(1)/0 tail.
// Pass B: K,V dbuf-2, stage kt+1 after BAR, WAITV(0)@0 / WAITV(2) steady (2 = prev stores).
// Q direct from global (one-time); mask LDS (lane-broadcast reads).
__global__ __launch_bounds__(256, 6) void k_attn(const short* __restrict__ qh,
                                                 const short* __restrict__ kh,
                                                 const short* __restrict__ vt,
                                                 const float* __restrict__ mb,
                                                 float* __restrict__ attn,
                                                 short* __restrict__ ctx){
  __shared__ __align__(16) short Sh[12288];        // 24576 B
  const int t = threadIdx.x, l = t & 63, w = t >> 6;   // w 0..3
  const int lr = l & 15, lg = l >> 4;
  int lin = blockIdx.y * 32 + blockIdx.x;          // 1024 wgs
  int sw = (lin & 7) * 128 + (lin >> 3);           // XCD-contiguous
  const int bh = sw >> 5, b = bh >> 3, h = bh & 7;
  const int q0 = (sw & 31) * 64;
  const short* Qb = qh + (size_t)bh * S_ * DP_ + (size_t)q0 * DP_;
  const short* Kb = kh + (size_t)bh * S_ * DP_;
  const short* Vtb = vt + (size_t)bh * DP_ * S_;
  const float* Mbb = mb + b * S_;
  float* Mlds = (float*)Sh;                        // 8KB
  short* SlabA = Sh + 4096;                        // pass A ring-3 (3 x 2048 shorts)
  short* KB = Sh + 4096;                           // pass B K dbuf-2
  short* VB = Sh + 8192;                           // pass B V dbuf-2
  const float scale2 = 0.125f * 1.442695041f;

  // prologue: Q direct (2 loads), mask (2 ops), K0, K1
  short8 bq0, bq1;
  {
    const short* qr = Qb + (size_t)(w * 16 + lr) * DP_;
    bq0 = *reinterpret_cast<const short8*>(qr + lg * 8);
    bq1 = *reinterpret_cast<const short8*>(qr + 32 + lg * 8);
  }
  #pragma unroll
  for(int i = 0; i < 2; ++i){
    int byte = (w*2 + i)*1024 + l*16;
    __builtin_amdgcn_global_load_lds(
        (const __attribute__((address_space(1))) void*)((const char*)Mbb + byte),
        (__attribute__((address_space(3))) void*)((char*)Mlds + byte), 16, 0, 0);
  }
  stage_k32(Kb, SlabA, w, l);
  stage_k32(Kb + 32*DP_, SlabA + 2048, w, l);
  WAITV(2); BAR();                                 // Q+mask retired; K0,K1 in flight
  const int grow = ((lr >> 2) << 3) + (lr & 3);    // permuted A-row base (0..27)

  // ---------------- pass A: row sums ----------------
  float ps = 0.f;
  for(int kt = 0; kt < NT2_; ++kt){
    if(kt < NT2_ - 1){ WAITV(1); } else { WAITV(0); }
    BAR();
    if(kt + 2 < NT2_)
      stage_k32(Kb + (size_t)(kt + 2) * 32 * DP_, SlabA + ((kt + 2) % 3) * 2048, w, l);
    const short* Kc = SlabA + (kt % 3) * 2048;
    const float* Ml = Mlds + kt * 32;
    #pragma unroll
    for(int h4 = 0; h4 < 2; ++h4){
      const int row = grow + h4 * 4;
      const int mcol = h4 * 4 + lg * 8;
      const float4 mv = *reinterpret_cast<const float4*>(&Ml[mcol]);
      short8 ak0 = *reinterpret_cast<const short8*>(&Kc[SWZ2(row, lg * 8)]);
      short8 ak1 = *reinterpret_cast<const short8*>(&Kc[SWZ2(row, 32 + lg * 8)]);
      __builtin_amdgcn_s_setprio(1);
      f32x4 c = {};
      c = __builtin_amdgcn_mfma_f32_16x16x32_bf16(ak0, bq0, c, 0, 0, 0);
      c = __builtin_amdgcn_mfma_f32_16x16x32_bf16(ak1, bq1, c, 0, 0, 0);
      __builtin_amdgcn_s_setprio(0);
      ps += __builtin_amdgcn_exp2f(__builtin_fmaf(c[0], scale2, mv.x));
      ps += __builtin_amdgcn_exp2f(__builtin_fmaf(c[1], scale2, mv.y));
      ps += __builtin_amdgcn_exp2f(__builtin_fmaf(c[2], scale2, mv.z));
      ps += __builtin_amdgcn_exp2f(__builtin_fmaf(c[3], scale2, mv.w));
    }
  }
  ps += __shfl_xor(ps, 16, 64);
  ps += __shfl_xor(ps, 32, 64);
  const float rinv = 1.f / ps;

  // ---------------- pass B: attn write + in-register PV ----------------
  BAR();                                           // all pass-A slab reads done
  stage_k32(Kb, KB, w, l);
  stage_v32(Vtb, VB, w, l);
  f32x4 o[4] = {};
  const int qg = q0 + w * 16 + lr;
  for(int kt = 0; kt < NT2_; ++kt){
    if(kt == 0){ WAITV(0); } else { WAITV(2); }
    BAR();
    if(kt + 1 < NT2_){
      stage_k32(Kb + (size_t)(kt + 1) * 32 * DP_, KB + ((kt + 1) & 1) * 2048, w, l);
      stage_v32(Vtb + (kt + 1) * 32, VB + ((kt + 1) & 1) * 2048, w, l);
    }
    const short* Kc = KB + (kt & 1) * 2048;
    const short* Vc = VB + (kt & 1) * 2048;
    const float* Ml = Mlds + kt * 32;
    i32x4 pav;
    #pragma unroll
    for(int h4 = 0; h4 < 2; ++h4){
      const int row = grow + h4 * 4;
      const int mcol = h4 * 4 + lg * 8;
      const float4 mv = *reinterpret_cast<const float4*>(&Ml[mcol]);
      short8 ak0 = *reinterpret_cast<const short8*>(&Kc[SWZ2(row, lg * 8)]);
      short8 ak1 = *reinterpret_cast<const short8*>(&Kc[SWZ2(row, 32 + lg * 8)]);
      __builtin_amdgcn_s_setprio(1);
      f32x4 c = {};
      c = __builtin_amdgcn_mfma_f32_16x16x32_bf16(ak0, bq0, c, 0, 0, 0);
      c = __builtin_amdgcn_mfma_f32_16x16x32_bf16(ak1, bq1, c, 0, 0, 0);
      __builtin_amdgcn_s_setprio(0);
      float4 pw;
      pw.x = __builtin_amdgcn_exp2f(__builtin_fmaf(c[0], scale2, mv.x)) * rinv;
      pw.y = __builtin_amdgcn_exp2f(__builtin_fmaf(c[1], scale2, mv.y)) * rinv;
      pw.z = __builtin_amdgcn_exp2f(__builtin_fmaf(c[2], scale2, mv.z)) * rinv;
      pw.w = __builtin_amdgcn_exp2f(__builtin_fmaf(c[3], scale2, mv.w)) * rinv;
      *reinterpret_cast<float4*>(&attn[((size_t)bh * S_ + qg) * S_ + kt * 32 + mcol]) = pw;
      pav[h4 * 2 + 0] = cvtpk(pw.x, pw.y);
      pav[h4 * 2 + 1] = cvtpk(pw.z, pw.w);
    }
    short8 pa = __builtin_bit_cast(short8, pav);
    __builtin_amdgcn_s_setprio(1);
    #pragma unroll
    for(int dt = 0; dt < 4; ++dt){
      const int d = dt * 16 + lr;
      short8 vb = *reinterpret_cast<const short8*>(&Vc[d * 32 + ((lg ^ (d & 3)) * 8)]);
      o[dt] = __builtin_amdgcn_mfma_f32_16x16x32_bf16(pa, vb, o[dt], 0, 0, 0);
    }
    __builtin_amdgcn_s_setprio(0);
  }
  // ctx write (head-merged bf16 [B][S][512])
  #pragma unroll
  for(int dt = 0; dt < 4; ++dt){
    #pragma unroll
    for(int r = 0; r < 4; ++r){
      int qq = q0 + w * 16 + lg * 4 + r;
      int dd = h * 64 + dt * 16 + lr;
      ctx[((size_t)b * S_ + qq) * D_ + dd] = f2bf(o[dt][r]);
    }
  }
}

extern "C" void kernel_launch(void* const* d_in, const int* in_sizes, int n_in,
                              void* d_out, int out_size, void* d_ws, size_t ws_size,
                              hipStream_t stream){
  const float* q  = (const float*)d_in[0];
  const float* k  = (const float*)d_in[1];
  const float* v  = (const float*)d_in[2];
  const int* mask = (const int*)d_in[3];
  const float* wq = (const float*)d_in[4];
  const float* bq = (const float*)d_in[5];
  const float* wk = (const float*)d_in[6];
  const float* bk = (const float*)d_in[7];
  const float* wv = (const float*)d_in[8];
  const float* bv = (const float*)d_in[9];
  const float* wo = (const float*)d_in[10];
  const float* bo = (const float*)d_in[11];

  float* out  = (float*)d_out;
  float* attn = out + (size_t)B_ * S_ * D_;

  char* ws = (char*)d_ws;
  short* qh  = (short*)(ws);                       // bf16 [B][H][S][64]
  short* kh  = (short*)(ws + 8388608);
  short* vvt = (short*)(ws + 16777216);            // bf16 [B][H][64][S]
  short* ctx = (short*)(ws + 25165824);            // bf16 [B][S][512]
  short* wT  = (short*)(ws + 33554432);            // bf16 [512][512] x4 transposed
  float* mb  = (float*)(ws + 33554432 + 4 * 524288);  // f32 [B][S] mask bias (exp2 domain)

  hipLaunchKernelGGL(k_pre, dim3(1056), dim3(256), 0, stream,
                     mask, wq, wk, wv, wo, wT, mb);

  hipLaunchKernelGGL(k_gemm_qkv, dim3(64, 4, 3), dim3(256), 0, stream,
                     q, k, v, wT, bq, bk, bv, qh, kh, vvt);

  hipLaunchKernelGGL(k_attn, dim3(32, 32), dim3(256), 0, stream, qh, kh, vvt, mb, attn, ctx);

  hipLaunchKernelGGL(k_gemm_out, dim3(64, 4), dim3(256), 0, stream, ctx, wT + 3 * 262144, bo, out);
}

// Round 19
// 222.760 us; speedup vs baseline: 1.5679x; 1.1834x over previous
//
#include <hip/hip_runtime.h>

#define B_ 4
#define S_ 2048
#define D_ 512
#define H_ 8
#define DP_ 64
#define NT_ (S_/64)

typedef __attribute__((ext_vector_type(4))) float f32x4;
typedef __attribute__((ext_vector_type(8))) short short8;
typedef __attribute__((ext_vector_type(4))) int i32x4;

__device__ __forceinline__ short f2bf(float f){
  unsigned u = __float_as_uint(f);
  u += 0x7fff + ((u >> 16) & 1);   // round-to-nearest-even
  return (short)(u >> 16);
}

__device__ __forceinline__ int cvtpk(float lo, float hi){
  int r;
  asm("v_cvt_pk_bf16_f32 %0, %1, %2" : "=v"(r) : "v"(lo), "v"(hi));
  return r;
}

// GEMM swizzle: XOR 8-elem granule with row&7
#define SWZ(r, kb) ((r)*64 + ((kb) ^ (((r)&7)<<3)))
// attn swizzle: f(row) = (row&3) | ((row>>3)&1)<<2  (2-way for linear and permuted reads)
#define F2(r) ((((r)&3)) | ((((r)>>3)&1)<<2))
#define SWZ2(r, kb) ((r)*64 + ((kb) ^ (F2(r)<<3)))

#define WAITV(N) do{ asm volatile("s_waitcnt vmcnt(" #N ")" ::: "memory"); }while(0)
#define WAITLGKM() do{ asm volatile("s_waitcnt lgkmcnt(0)" ::: "memory"); }while(0)
#define BAR() do{ __builtin_amdgcn_s_barrier(); __builtin_amdgcn_sched_barrier(0); }while(0)

template<int NC>
__device__ __forceinline__ void stage_swz(const short* __restrict__ g, int rowStride,
                                          short* shbase, int w, int l){
  #pragma unroll
  for(int i = 0; i < NC; ++i){
    int byte = (w*NC + i)*1024 + l*16;
    int row = byte >> 7;
    int gs = ((byte >> 4) & 7) ^ (row & 7);
    const short* src = g + (size_t)row*rowStride + gs*8;
    __builtin_amdgcn_global_load_lds((const __attribute__((address_space(1))) void*)src,
        (__attribute__((address_space(3))) void*)(shbase + (w*NC + i)*512), 16, 0, 0);
  }
}
template<int NC>
__device__ __forceinline__ void stage_swz2(const short* __restrict__ g, int rowStride,
                                           short* shbase, int w, int l){
  #pragma unroll
  for(int i = 0; i < NC; ++i){
    int byte = (w*NC + i)*1024 + l*16;
    int row = byte >> 7;
    int gs = ((byte >> 4) & 7) ^ F2(row);
    const short* src = g + (size_t)row*rowStride + gs*8;
    __builtin_amdgcn_global_load_lds((const __attribute__((address_space(1))) void*)src,
        (__attribute__((address_space(3))) void*)(shbase + (w*NC + i)*512), 16, 0, 0);
  }
}

// ---------------- pre-pass: weight transposes + mask bias (exp2 domain) ----------------
__global__ __launch_bounds__(256) void k_pre(const int* __restrict__ mask,
        const float* __restrict__ w0, const float* __restrict__ w1,
        const float* __restrict__ w2, const float* __restrict__ w3,
        short* __restrict__ wT, float* __restrict__ mb){
  __shared__ float tt[32][33];
  const int bi = blockIdx.x, t = threadIdx.x;
  if(bi < 1024){
    const int z = bi >> 8;
    const float* w = z == 0 ? w0 : z == 1 ? w1 : z == 2 ? w2 : w3;
    short* wt = wT + z * 262144;
    const int bxy = bi & 255;
    const int bx = (bxy & 15) * 32, by = (bxy >> 4) * 32;
    const int tx = t & 31, ty = t >> 5;
    #pragma unroll
    for(int i = 0; i < 32; i += 8) tt[ty + i][tx] = w[(by + ty + i) * D_ + bx + tx];
    __syncthreads();
    #pragma unroll
    for(int i = 0; i < 32; i += 8) wt[(bx + ty + i) * D_ + by + tx] = f2bf(tt[tx][ty + i]);
  } else {
    int i = (bi - 1024) * 256 + t;
    mb[i] = mask[i] ? -1.442695041e9f : 0.0f;
  }
}

// ---------------- fused QKV GEMM: X f32 read + convert in-staging ----------------
__global__ __launch_bounds__(256) void k_gemm_qkv(const float* __restrict__ qf,
        const float* __restrict__ kf, const float* __restrict__ vf,
        const short* __restrict__ WTall, const float* __restrict__ b0,
        const float* __restrict__ b1, const float* __restrict__ b2,
        short* __restrict__ qh, short* __restrict__ kh, short* __restrict__ vvt){
  __shared__ __align__(16) short As[8192];
  __shared__ __align__(16) short Bs[8192];
  const int z = blockIdx.z;
  const float* X = z == 0 ? qf : (z == 1 ? kf : vf);
  const short* WT = WTall + (size_t)z * (D_*D_);
  const float* bias = z==0 ? b0 : (z==1 ? b1 : b2);
  const int t = threadIdx.x, l = t & 63, w = t >> 6;
  const int lr = l & 15, lg = l >> 4;
  const int m0 = blockIdx.x * 128, n0 = blockIdx.y * 128;
  const int wr = w >> 1, wc = w & 1;
  const float* Xb = X + (size_t)m0 * D_;
  const short* Wb = WT + (size_t)n0 * D_;
  f32x4 acc[4][4] = {};
  for(int kt = 0; kt < D_ / 64; ++kt){
    #pragma unroll
    for(int i = 0; i < 4; ++i){
      int e = t + 256 * i;
      int row = e >> 3, c8 = (e & 7) * 8;
      const float* src = Xb + (size_t)row * D_ + kt * 64 + c8;
      float4 f0 = *reinterpret_cast<const float4*>(src);
      float4 f1 = *reinterpret_cast<const float4*>(src + 4);
      i32x4 pk;
      pk[0] = cvtpk(f0.x, f0.y); pk[1] = cvtpk(f0.z, f0.w);
      pk[2] = cvtpk(f1.x, f1.y); pk[3] = cvtpk(f1.z, f1.w);
      *reinterpret_cast<i32x4*>(&As[SWZ(row, c8)]) = pk;
    }
    stage_swz<4>(Wb + kt*64, D_, Bs, w, l);
    __syncthreads();
    #pragma unroll
    for(int ks = 0; ks < 2; ++ks){
      const int kb = ks*32 + lg*8;
      short8 a[4], b[4];
      #pragma unroll
      for(int mt = 0; mt < 4; ++mt)
        a[mt] = *reinterpret_cast<const short8*>(&As[SWZ(wr*64 + mt*16 + lr, kb)]);
      #pragma unroll
      for(int nt = 0; nt < 4; ++nt)
        b[nt] = *reinterpret_cast<const short8*>(&Bs[SWZ(wc*64 + nt*16 + lr, kb)]);
      __builtin_amdgcn_s_setprio(1);
      #pragma unroll
      for(int mt = 0; mt < 4; ++mt)
        #pragma unroll
        for(int nt = 0; nt < 4; ++nt)
          acc[mt][nt] = __builtin_amdgcn_mfma_f32_16x16x32_bf16(a[mt], b[nt], acc[mt][nt], 0, 0, 0);
      __builtin_amdgcn_s_setprio(0);
    }
    __syncthreads();
  }
  #pragma unroll
  for(int mt = 0; mt < 4; ++mt){
    #pragma unroll
    for(int nt = 0; nt < 4; ++nt){
      const int n = n0 + wc*64 + nt*16 + lr;
      const int m4 = m0 + wr*64 + mt*16 + lg*4;
      float vals[4];
      #pragma unroll
      for(int r = 0; r < 4; ++r) vals[r] = acc[mt][nt][r] + bias[n];
      if(z == 2){
        short4 pv4;
        pv4.x = f2bf(vals[0]); pv4.y = f2bf(vals[1]); pv4.z = f2bf(vals[2]); pv4.w = f2bf(vals[3]);
        *reinterpret_cast<short4*>(&vvt[
            (((size_t)((m4 >> 11) * H_ + (n >> 6))) * DP_ + (n & 63)) * S_ + (m4 & 2047)]) = pv4;
      } else {
        short* dst = z == 0 ? qh : kh;
        #pragma unroll
        for(int r = 0; r < 4; ++r){
          int m = m4 + r;
          dst[(((size_t)((m >> 11) * H_ + (n >> 6))) * S_ + (m & 2047)) * DP_ + (n & 63)] = f2bf(vals[r]);
        }
      }
    }
  }
}

// ---------------- out GEMM: ctx[8192,512]bf16 @ woT + bo -> f32 ----------------
__global__ __launch_bounds__(256) void k_gemm_out(const short* __restrict__ X,
        const short* __restrict__ WT, const float* __restrict__ bias,
        float* __restrict__ Out){
  __shared__ __align__(16) short As[8192];
  __shared__ __align__(16) short Bs[8192];
  const int t = threadIdx.x, l = t & 63, w = t >> 6;
  const int lr = l & 15, lg = l >> 4;
  const int m0 = blockIdx.x * 128, n0 = blockIdx.y * 128;
  const int wr = w >> 1, wc = w & 1;
  const short* Xb = X + (size_t)m0 * D_;
  const short* Wb = WT + (size_t)n0 * D_;
  f32x4 acc[4][4] = {};
  for(int kt = 0; kt < D_ / 64; ++kt){
    stage_swz<4>(Xb + kt*64, D_, As, w, l);
    stage_swz<4>(Wb + kt*64, D_, Bs, w, l);
    __syncthreads();
    #pragma unroll
    for(int ks = 0; ks < 2; ++ks){
      const int kb = ks*32 + lg*8;
      short8 a[4], b[4];
      #pragma unroll
      for(int mt = 0; mt < 4; ++mt)
        a[mt] = *reinterpret_cast<const short8*>(&As[SWZ(wr*64 + mt*16 + lr, kb)]);
      #pragma unroll
      for(int nt = 0; nt < 4; ++nt)
        b[nt] = *reinterpret_cast<const short8*>(&Bs[SWZ(wc*64 + nt*16 + lr, kb)]);
      __builtin_amdgcn_s_setprio(1);
      #pragma unroll
      for(int mt = 0; mt < 4; ++mt)
        #pragma unroll
        for(int nt = 0; nt < 4; ++nt)
          acc[mt][nt] = __builtin_amdgcn_mfma_f32_16x16x32_bf16(a[mt], b[nt], acc[mt][nt], 0, 0, 0);
      __builtin_amdgcn_s_setprio(0);
    }
    __syncthreads();
  }
  #pragma unroll
  for(int mt = 0; mt < 4; ++mt){
    #pragma unroll
    for(int nt = 0; nt < 4; ++nt){
      const int n = n0 + wc*64 + nt*16 + lr;
      const int m4 = m0 + wr*64 + mt*16 + lg*4;
      #pragma unroll
      for(int r = 0; r < 4; ++r)
        Out[(size_t)(m4 + r) * D_ + n] = acc[mt][nt][r] + bias[n];
    }
  }
}

// ---------------- fused attention: k-split waves, 2 q-subtiles/wave (R14 + exp2) ----------------
// 8 waves, q-tile 128. Wave (wq=w&3, g=w>>2): per pair-iter computes tile 2i+g over
// q-rows wq*32..wq*32+31 (2 qs). Partial softmax sums / PV outputs combined via LDS.
// LDS bytes: mask [0,8192); slab [8192,57344): pass A K ring-6, pass B K dbuf-4 [8192,40960)
//            + V dbuf-4 [40960,73728) (V slots 2,3 overlay Q [57344,73728));
//            psums [73728,74752). Total 74752 B -> 2 blocks/CU, 16 waves/CU.
// Pass A: stage pair(i+2) after BAR, WAITV(2)/0; pass B: stage pair(i+1) after BAR (i>=1),
// WAITV(4)@0 / 8 steady (8 = attn stores of prev iter).
__global__ __launch_bounds__(512, 4) void k_attn(const short* __restrict__ qh,
                                                 const short* __restrict__ kh,
                                                 const short* __restrict__ vt,
                                                 const float* __restrict__ mb,
                                                 float* __restrict__ attn,
                                                 short* __restrict__ ctx){
  __shared__ __align__(16) short Sh[37376];
  const int t = threadIdx.x, l = t & 63, w = t >> 6;
  const int lr = l & 15, lg = l >> 4;
  const int wq = w & 3, g = w >> 2;
  int lin = blockIdx.y * 16 + blockIdx.x;
  int sw = (lin & 7) * 64 + (lin >> 3);
  const int bh = sw >> 4, b = bh >> 3, h = bh & 7;
  const int q0 = (sw & 15) * 128;
  const short* Qb = qh + (size_t)bh * S_ * DP_ + (size_t)q0 * DP_;
  const short* Kb = kh + (size_t)bh * S_ * DP_;
  const short* Vtb = vt + (size_t)bh * DP_ * S_;
  const float* Mbb = mb + b * S_;
  float* Mlds = (float*)Sh;                        // [0,8192) B
  short* KA = Sh + 4096;                           // pass A ring-6 singles (slot*4096 shorts)
  short* KB = Sh + 4096;                           // pass B K dbuf-4
  short* VB = Sh + 20480;                          // pass B V dbuf-4
  short* Qs = Sh + 28672;                          // Q 16KB [57344,73728) B
  float* Ps_ = (float*)(Sh + 36864);               // psums 1KB [73728,74752) B
  const float scale2 = 0.125f * 1.442695041f;      // exp2 domain

  // prologue: mask(1), Q(2), K0..K3 (4)
  __builtin_amdgcn_global_load_lds(
      (const __attribute__((address_space(1))) void*)(Mbb + w*256 + l*4),
      (__attribute__((address_space(3))) void*)(Mlds + w*256 + l*4), 16, 0, 0);
  stage_swz2<2>(Qb, DP_, Qs, w, l);
  stage_swz2<1>(Kb,          DP_, KA,          w, l);
  stage_swz2<1>(Kb + 4096,   DP_, KA + 4096,   w, l);
  stage_swz2<1>(Kb + 2*4096, DP_, KA + 2*4096, w, l);
  stage_swz2<1>(Kb + 3*4096, DP_, KA + 3*4096, w, l);
  WAITV(4); BAR();                                 // mask+Q landed; K0..K3 in flight
  short8 bq[2][2];
  #pragma unroll
  for(int qs = 0; qs < 2; ++qs){
    int r = wq * 32 + qs * 16 + lr;
    bq[qs][0] = *reinterpret_cast<const short8*>(&Qs[SWZ2(r, lg * 8)]);
    bq[qs][1] = *reinterpret_cast<const short8*>(&Qs[SWZ2(r, 32 + lg * 8)]);
  }
  const int grow = ((lr >> 2) << 3) + (lr & 3);    // permuted A-row base

  // ---------------- pass A: partial row sums (tile 2i+g per wave, 2 qs) ----------------
  float ps2[2] = {0.f, 0.f};
  for(int i = 0; i < NT_/2; ++i){
    if(i < NT_/2 - 1){ WAITV(2); } else { WAITV(0); }
    BAR();
    if(i + 2 < NT_/2){
      int tfa = 2*i + 4, tfb = 2*i + 5;
      stage_swz2<1>(Kb + (size_t)tfa * 4096, DP_, KA + (tfa % 6) * 4096, w, l);
      stage_swz2<1>(Kb + (size_t)tfb * 4096, DP_, KA + (tfb % 6) * 4096, w, l);
    }
    const int kt = 2*i + g;
    const short* Kc = KA + (kt % 6) * 4096;
    const float* Ml = Mlds + kt * 64;
    #pragma unroll
    for(int st = 0; st < 4; ++st){
      const int ks = st >> 1, h4 = st & 1;
      const int row = grow + h4 * 4 + ks * 32;
      const int mcol = ks * 32 + h4 * 4 + lg * 8;
      const float4 mv = *(const float4*)&Ml[mcol];
      short8 ak0 = *reinterpret_cast<const short8*>(&Kc[SWZ2(row, lg * 8)]);
      short8 ak1 = *reinterpret_cast<const short8*>(&Kc[SWZ2(row, 32 + lg * 8)]);
      __builtin_amdgcn_s_setprio(1);
      f32x4 c0 = {}, c1 = {};
      c0 = __builtin_amdgcn_mfma_f32_16x16x32_bf16(ak0, bq[0][0], c0, 0, 0, 0);
      c0 = __builtin_amdgcn_mfma_f32_16x16x32_bf16(ak1, bq[0][1], c0, 0, 0, 0);
      c1 = __builtin_amdgcn_mfma_f32_16x16x32_bf16(ak0, bq[1][0], c1, 0, 0, 0);
      c1 = __builtin_amdgcn_mfma_f32_16x16x32_bf16(ak1, bq[1][1], c1, 0, 0, 0);
      __builtin_amdgcn_s_setprio(0);
      ps2[0] += __builtin_amdgcn_exp2f(__builtin_fmaf(c0[0], scale2, mv.x));
      ps2[0] += __builtin_amdgcn_exp2f(__builtin_fmaf(c0[1], scale2, mv.y));
      ps2[0] += __builtin_amdgcn_exp2f(__builtin_fmaf(c0[2], scale2, mv.z));
      ps2[0] += __builtin_amdgcn_exp2f(__builtin_fmaf(c0[3], scale2, mv.w));
      ps2[1] += __builtin_amdgcn_exp2f(__builtin_fmaf(c1[0], scale2, mv.x));
      ps2[1] += __builtin_amdgcn_exp2f(__builtin_fmaf(c1[1], scale2, mv.y));
      ps2[1] += __builtin_amdgcn_exp2f(__builtin_fmaf(c1[2], scale2, mv.z));
      ps2[1] += __builtin_amdgcn_exp2f(__builtin_fmaf(c1[3], scale2, mv.w));
    }
  }
  // reduce over lg, publish partials, combine with partner k-group
  #pragma unroll
  for(int qs = 0; qs < 2; ++qs){
    ps2[qs] += __shfl_xor(ps2[qs], 16, 64);
    ps2[qs] += __shfl_xor(ps2[qs], 32, 64);
  }
  Ps_[(w*2 + 0)*16 + lr] = ps2[0];
  Ps_[(w*2 + 1)*16 + lr] = ps2[1];
  WAITLGKM(); BAR();                               // psums visible; pass-A reads all consumed
  // pass B prologue stages (tiles 0-3 K and V)
  stage_swz2<1>(Kb,          DP_, KB,          w, l);
  stage_swz2<1>(Kb + 4096,   DP_, KB + 4096,   w, l);
  stage_swz2<1>(Vtb,         S_,  VB,          w, l);
  stage_swz2<1>(Vtb + 64,    S_,  VB + 4096,   w, l);
  stage_swz2<1>(Kb + 2*4096, DP_, KB + 2*4096, w, l);
  stage_swz2<1>(Kb + 3*4096, DP_, KB + 3*4096, w, l);
  stage_swz2<1>(Vtb + 2*64,  S_,  VB + 2*4096, w, l);
  stage_swz2<1>(Vtb + 3*64,  S_,  VB + 3*4096, w, l);
  const float rinv0 = 1.f / (ps2[0] + Ps_[((w^4)*2 + 0)*16 + lr]);
  const float rinv1 = 1.f / (ps2[1] + Ps_[((w^4)*2 + 1)*16 + lr]);

  // ---------------- pass B: attn write + in-register PV (tile 2i+g per wave, 2 qs) ----------------
  f32x4 o[2][4] = {};
  for(int i = 0; i < NT_/2; ++i){
    if(i == 0){ WAITV(4); } else { WAITV(8); }
    BAR();
    if(i >= 1 && i + 1 < NT_/2){
      int tfa = 2*i + 2, tfb = 2*i + 3;
      stage_swz2<1>(Kb + (size_t)tfa * 4096, DP_, KB + (tfa & 3) * 4096, w, l);
      stage_swz2<1>(Kb + (size_t)tfb * 4096, DP_, KB + (tfb & 3) * 4096, w, l);
      stage_swz2<1>(Vtb + (size_t)tfa * 64,  S_,  VB + (tfa & 3) * 4096, w, l);
      stage_swz2<1>(Vtb + (size_t)tfb * 64,  S_,  VB + (tfb & 3) * 4096, w, l);
    }
    const int kt = 2*i + g;
    const short* Kc = KB + (kt & 3) * 4096;
    const short* Vc = VB + (kt & 3) * 4096;
    const float* Ml = Mlds + kt * 64;
    i32x4 pav[2][2];
    #pragma unroll
    for(int st = 0; st < 4; ++st){
      const int ks = st >> 1, h4 = st & 1;
      const int row = grow + h4 * 4 + ks * 32;
      const int mcol = ks * 32 + h4 * 4 + lg * 8;
      const float4 mv = *(const float4*)&Ml[mcol];
      short8 ak0 = *reinterpret_cast<const short8*>(&Kc[SWZ2(row, lg * 8)]);
      short8 ak1 = *reinterpret_cast<const short8*>(&Kc[SWZ2(row, 32 + lg * 8)]);
      __builtin_amdgcn_s_setprio(1);
      f32x4 c0 = {}, c1 = {};
      c0 = __builtin_amdgcn_mfma_f32_16x16x32_bf16(ak0, bq[0][0], c0, 0, 0, 0);
      c0 = __builtin_amdgcn_mfma_f32_16x16x32_bf16(ak1, bq[0][1], c0, 0, 0, 0);
      c1 = __builtin_amdgcn_mfma_f32_16x16x32_bf16(ak0, bq[1][0], c1, 0, 0, 0);
      c1 = __builtin_amdgcn_mfma_f32_16x16x32_bf16(ak1, bq[1][1], c1, 0, 0, 0);
      __builtin_amdgcn_s_setprio(0);
      float4 pw0, pw1;
      pw0.x = __builtin_amdgcn_exp2f(__builtin_fmaf(c0[0], scale2, mv.x)) * rinv0;
      pw0.y = __builtin_amdgcn_exp2f(__builtin_fmaf(c0[1], scale2, mv.y)) * rinv0;
      pw0.z = __builtin_amdgcn_exp2f(__builtin_fmaf(c0[2], scale2, mv.z)) * rinv0;
      pw0.w = __builtin_amdgcn_exp2f(__builtin_fmaf(c0[3], scale2, mv.w)) * rinv0;
      pw1.x = __builtin_amdgcn_exp2f(__builtin_fmaf(c1[0], scale2, mv.x)) * rinv1;
      pw1.y = __builtin_amdgcn_exp2f(__builtin_fmaf(c1[1], scale2, mv.y)) * rinv1;
      pw1.z = __builtin_amdgcn_exp2f(__builtin_fmaf(c1[2], scale2, mv.z)) * rinv1;
      pw1.w = __builtin_amdgcn_exp2f(__builtin_fmaf(c1[3], scale2, mv.w)) * rinv1;
      const int qr = q0 + wq * 32 + lr;
      *reinterpret_cast<float4*>(&attn[((size_t)bh * S_ + qr) * S_ + kt * 64 + mcol]) = pw0;
      *reinterpret_cast<float4*>(&attn[((size_t)bh * S_ + qr + 16) * S_ + kt * 64 + mcol]) = pw1;
      pav[0][ks][h4 * 2 + 0] = cvtpk(pw0.x, pw0.y);
      pav[0][ks][h4 * 2 + 1] = cvtpk(pw0.z, pw0.w);
      pav[1][ks][h4 * 2 + 0] = cvtpk(pw1.x, pw1.y);
      pav[1][ks][h4 * 2 + 1] = cvtpk(pw1.z, pw1.w);
    }
    #pragma unroll
    for(int ks = 0; ks < 2; ++ks){
      short8 pa0 = __builtin_bit_cast(short8, pav[0][ks]);
      short8 pa1 = __builtin_bit_cast(short8, pav[1][ks]);
      __builtin_amdgcn_s_setprio(1);
      #pragma unroll
      for(int dt = 0; dt < 4; ++dt){
        short8 vb = *reinterpret_cast<const short8*>(&Vc[SWZ2(dt * 16 + lr, ks * 32 + lg * 8)]);
        o[0][dt] = __builtin_amdgcn_mfma_f32_16x16x32_bf16(pa0, vb, o[0][dt], 0, 0, 0);
        o[1][dt] = __builtin_amdgcn_mfma_f32_16x16x32_bf16(pa1, vb, o[1][dt], 0, 0, 0);
      }
      __builtin_amdgcn_s_setprio(0);
    }
  }

  // ---------------- o-combine across k-groups, write ctx ----------------
  BAR();                                           // all pass-B slab reads consumed
  float* Oc = (float*)(Sh + 4096);                 // 33.3KB scratch (stride 65)
  if(g == 0){
    #pragma unroll
    for(int qs = 0; qs < 2; ++qs)
      #pragma unroll
      for(int dt = 0; dt < 4; ++dt)
        #pragma unroll
        for(int r = 0; r < 4; ++r)
          Oc[(wq*32 + qs*16 + lg*4 + r) * 65 + dt*16 + lr] = o[qs][dt][r];
  }
  WAITLGKM(); BAR();
  if(g == 1){
    #pragma unroll
    for(int qs = 0; qs < 2; ++qs){
      #pragma unroll
      for(int dt = 0; dt < 4; ++dt){
        #pragma unroll
        for(int r = 0; r < 4; ++r){
          float v = o[qs][dt][r] + Oc[(wq*32 + qs*16 + lg*4 + r) * 65 + dt*16 + lr];
          int qg = q0 + wq*32 + qs*16 + lg*4 + r;
          int dd = h * 64 + dt * 16 + lr;
          ctx[((size_t)b * S_ + qg) * D_ + dd] = f2bf(v);
        }
      }
    }
  }
}

extern "C" void kernel_launch(void* const* d_in, const int* in_sizes, int n_in,
                              void* d_out, int out_size, void* d_ws, size_t ws_size,
                              hipStream_t stream){
  const float* q  = (const float*)d_in[0];
  const float* k  = (const float*)d_in[1];
  const float* v  = (const float*)d_in[2];
  const int* mask = (const int*)d_in[3];
  const float* wq = (const float*)d_in[4];
  const float* bq = (const float*)d_in[5];
  const float* wk = (const float*)d_in[6];
  const float* bk = (const float*)d_in[7];
  const float* wv = (const float*)d_in[8];
  const float* bv = (const float*)d_in[9];
  const float* wo = (const float*)d_in[10];
  const float* bo = (const float*)d_in[11];

  float* out  = (float*)d_out;
  float* attn = out + (size_t)B_ * S_ * D_;

  char* ws = (char*)d_ws;
  short* qh  = (short*)(ws);                       // bf16 [B][H][S][64]
  short* kh  = (short*)(ws + 8388608);
  short* vvt = (short*)(ws + 16777216);            // bf16 [B][H][64][S]
  short* ctx = (short*)(ws + 25165824);            // bf16 [B][S][512]
  short* wT  = (short*)(ws + 33554432);            // bf16 [512][512] x4 transposed
  float* mb  = (float*)(ws + 33554432 + 4 * 524288);  // f32 [B][S] mask bias (exp2 domain)

  hipLaunchKernelGGL(k_pre, dim3(1056), dim3(256), 0, stream,
                     mask, wq, wk, wv, wo, wT, mb);

  hipLaunchKernelGGL(k_gemm_qkv, dim3(64, 4, 3), dim3(256), 0, stream,
                     q, k, v, wT, bq, bk, bv, qh, kh, vvt);

  hipLaunchKernelGGL(k_attn, dim3(16, 32), dim3(512), 0, stream, qh, kh, vvt, mb, attn, ctx);

  hipLaunchKernelGGL(k_gemm_out, dim3(64, 4), dim3(256), 0, stream, ctx, wT + 3 * 262144, bo, out);
}